// Round 10
// baseline (1496.267 us; speedup 1.0000x reference)
//
#include <hip/hip_runtime.h>
#include <math.h>

#define BB 4
#define NN 2048
#define KK 20
#define NEG 0.2f

// d_out layout: sim(4) q1(3200) q2(3200) e1(40) e2(40) xd1(3200) = 9684
#define QOFF0 4
#define QOFF1 3204
#define EOFF0 6404
#define EOFF1 6444
#define XDOFF 6484

// ---------------- transpose x (B,3,N) -> (B,N,3) + row norms ----------------
__global__ __launch_bounds__(256) void transpose_x_kernel(
    const float* __restrict__ x, float* __restrict__ fnc, float* __restrict__ xx)
{
    int gid = blockIdx.x * 256 + threadIdx.x;   // B*N = 8192
    int b = gid >> 11, n = gid & 2047;
    float s = 0.f;
#pragma unroll
    for (int c = 0; c < 3; ++c) {
        float v = x[((size_t)b * 3 + c) * NN + n];
        fnc[(size_t)gid * 3 + c] = v;
        s += v * v;
    }
    xx[gid] = s;
}

// ---------------- row norms of a h512 channel slice ----------------
__global__ __launch_bounds__(256) void norms_kernel(
    const float* __restrict__ h512, int choff, int C, float* __restrict__ xx)
{
    int gid = blockIdx.x * 256 + threadIdx.x;   // 8192
    const float* p = h512 + (size_t)gid * 512 + choff;
    float s = 0.f;
    for (int c = 0; c < C; ++c) { float v = p[c]; s += v * v; }
    xx[gid] = s;
}

// ---- DPP argmax step: combine with neighbor moved by CTRL (VALU, no LDS) ----
template<int CTRL>
__device__ __forceinline__ void dpp_step(float& v, int& i)
{
    int vi = __float_as_int(v);
    int nv = __builtin_amdgcn_update_dpp(vi, vi, CTRL, 0xf, 0xf, false);
    int ni = __builtin_amdgcn_update_dpp(i,  i,  CTRL, 0xf, 0xf, false);
    float nvf = __int_as_float(nv);
    if (nvf > v || (nvf == v && ni < i)) { v = nvf; i = ni; }
}

// 8-row x 4-col FMA block for one 4-channel group
__device__ __forceinline__ void knn_fma_group(
    const float4 f[4], const float4 cv[8],
    float a0[8], float a1[8], float a2[8], float a3[8])
{
#pragma unroll
    for (int r = 0; r < 8; ++r) {
        a0[r] += cv[r].x * f[0].x; a1[r] += cv[r].x * f[0].y;
        a2[r] += cv[r].x * f[0].z; a3[r] += cv[r].x * f[0].w;
        a0[r] += cv[r].y * f[1].x; a1[r] += cv[r].y * f[1].y;
        a2[r] += cv[r].y * f[1].z; a3[r] += cv[r].y * f[1].w;
        a0[r] += cv[r].z * f[2].x; a1[r] += cv[r].z * f[2].y;
        a2[r] += cv[r].z * f[2].z; a3[r] += cv[r].z * f[2].w;
        a0[r] += cv[r].w * f[3].x; a1[r] += cv[r].w * f[3].y;
        a2[r] += cv[r].w * f[3].z; a3[r] += cv[r].w * f[3].w;
    }
}

// ---------------- fused pairwise-dot + top-20 ----------------
// Dot phase: explicit 2-stage software pipeline (A/B group double-buffer,
// no rotate copies): while group A's 128 FMAs run, group B's 4 fb float4
// loads + 8 cv s_load_dwordx4 are in flight, and vice versa.
template<int C>
__global__ __launch_bounds__(512, 4) void knn_kernel(
    const float* __restrict__ fcn,   // (B,C,N)
    const float* __restrict__ fnc,   // rows of length ncs, center vectors at +choff
    int ncs, int choff,
    const float* __restrict__ xx, int* __restrict__ idxout)
{
    __shared__ float sbuf[8][NN];    // 64 KB
    int tid = threadIdx.x;
    int bid = blockIdx.x;            // 1024
    int b   = bid & 3;
    int n0  = (((bid >> 3) << 1) | ((bid >> 2) & 1)) * 8;   // covers 0..2047 per batch

    const float* fb = fcn + (size_t)b * C * NN;
    const float* xb = xx + b * NN;
    const float* cbase = fnc + (size_t)(b * NN + n0) * ncs + choff;

    float a0[8], a1[8], a2[8], a3[8];
#pragma unroll
    for (int r = 0; r < 8; ++r) { a0[r] = 0.f; a1[r] = 0.f; a2[r] = 0.f; a3[r] = 0.f; }

    const float* fp = fb + 4 * tid;

    if constexpr (C % 8 == 0) {
        float4 fA[4], fB[4];
        float4 cvA[8], cvB[8];
#pragma unroll
        for (int q = 0; q < 4; ++q) fA[q] = *(const float4*)(fp + (size_t)q * NN);
#pragma unroll
        for (int r = 0; r < 8; ++r) cvA[r] = *(const float4*)(cbase + (size_t)r * ncs);
#pragma unroll 1
        for (int cg = 0; cg < C; cg += 8) {
            // stage B loads (cg+4): in flight during A compute
#pragma unroll
            for (int q = 0; q < 4; ++q)
                fB[q] = *(const float4*)(fp + (size_t)(cg + 4 + q) * NN);
#pragma unroll
            for (int r = 0; r < 8; ++r)
                cvB[r] = *(const float4*)(cbase + (size_t)r * ncs + cg + 4);
            knn_fma_group(fA, cvA, a0, a1, a2, a3);
            // stage A loads for next iteration (cg+8): in flight during B compute
            if (cg + 8 < C) {
#pragma unroll
                for (int q = 0; q < 4; ++q)
                    fA[q] = *(const float4*)(fp + (size_t)(cg + 8 + q) * NN);
#pragma unroll
                for (int r = 0; r < 8; ++r)
                    cvA[r] = *(const float4*)(cbase + (size_t)r * ncs + cg + 8);
            }
            knn_fma_group(fB, cvB, a0, a1, a2, a3);
        }
    } else {
        for (int c = 0; c < C; ++c) {
            float cr[8];
#pragma unroll
            for (int r = 0; r < 8; ++r) cr[r] = cbase[(size_t)r * ncs + c];
            float4 v = *(const float4*)(fp + (size_t)c * NN);
#pragma unroll
            for (int r = 0; r < 8; ++r) {
                a0[r] += cr[r] * v.x; a1[r] += cr[r] * v.y;
                a2[r] += cr[r] * v.z; a3[r] += cr[r] * v.w;
            }
        }
    }
    {
        float4 xm = *(const float4*)(xb + 4 * tid);
#pragma unroll
        for (int r = 0; r < 8; ++r) {
            float4 sv = {2.f * a0[r] - xm.x, 2.f * a1[r] - xm.y,
                         2.f * a2[r] - xm.z, 2.f * a3[r] - xm.w};
            *(float4*)&sbuf[r][4 * tid] = sv;
        }
    }
    __syncthreads();

    // ---- select phase: wave w (0..7) handles row w
    int w = tid >> 6, lane = tid & 63;
    float* sb = sbuf[w];
    int* op = idxout + (size_t)(b * NN + n0 + w) * KK;
    const float NINF = -3.4e38f;

    float v1 = NINF, v2 = NINF; int i1 = -1, i2 = -1;
#pragma unroll 8
    for (int j = 0; j < 32; ++j) {
        int m = lane + (j << 6);
        float vv = sb[m];
        if (vv > v1) { v2 = v1; i2 = i1; v1 = vv; i1 = m; }
        else if (vv > v2) { v2 = vv; i2 = m; }
    }

    for (int it = 0; it < KK; ++it) {
        float bv = v1; int bi = i1;
        dpp_step<0x111>(bv, bi);   // row_shr:1
        dpp_step<0x112>(bv, bi);   // row_shr:2
        dpp_step<0x114>(bv, bi);   // row_shr:4
        dpp_step<0x118>(bv, bi);   // row_shr:8
        dpp_step<0x142>(bv, bi);   // row_bcast:15
        dpp_step<0x143>(bv, bi);   // row_bcast:31 -> lane 63 holds argmax
        int win = __builtin_amdgcn_readlane(bi, 63);
        if (lane == 0) op[it] = win;
        if (i1 == win) {           // owner lane consumes
            sb[win] = NINF;
            v1 = v2; i1 = i2;
            v2 = NINF; i2 = -1;
        }
        if (__any(v1 == NINF)) {   // rare rescan
            if (v1 == NINF) {
                v2 = NINF; i1 = -1; i2 = -1;
#pragma unroll 8
                for (int j = 0; j < 32; ++j) {
                    int m = lane + (j << 6);
                    float vv = sb[m];
                    if (vv > v1) { v2 = v1; i2 = i1; v1 = vv; i1 = m; }
                    else if (vv > v2) { v2 = vv; i2 = m; }
                }
            }
        }
    }
}

// ---------------- G = F*W1^T, H = F*(W2-W1)^T  (out layout (B*N, COUT)) ----
template<int C, int COUT>
__global__ __launch_bounds__(256) void gemm_gh_kernel(
    const float* __restrict__ fnc, int ncs, int choff,
    const float* __restrict__ W,     // (COUT, 2C)
    float* __restrict__ G, float* __restrict__ H)
{
    constexpr int GROUPS = 256 / COUT;
    constexpr int RPT = 8 / GROUPS;
    __shared__ float Fs[8][C];
    int tid = threadIdx.x;
    int row0 = blockIdx.x * 8;        // grid = B*N/8 = 1024
    for (int i = tid; i < 8 * C; i += 256) {
        int r = i / C, c = i % C;
        Fs[r][c] = fnc[(size_t)(row0 + r) * ncs + choff + c];
    }
    __syncthreads();
    int o = tid % COUT;
    int r0 = (tid / COUT) * RPT;
    float g[RPT], h[RPT];
#pragma unroll
    for (int r = 0; r < RPT; ++r) { g[r] = 0.f; h[r] = 0.f; }
    const float* wr = W + (size_t)o * 2 * C;
    for (int c = 0; c < C; ++c) {
        float w1 = wr[c], wd = wr[C + c] - w1;
#pragma unroll
        for (int r = 0; r < RPT; ++r) {
            float f = Fs[r0 + r][c];
            g[r] += f * w1; h[r] += f * wd;
        }
    }
#pragma unroll
    for (int r = 0; r < RPT; ++r) {
        size_t rr = (size_t)(row0 + r0 + r) * COUT + o;
        G[rr] = g[r]; H[rr] = h[r];
    }
}

// ---------------- gather y=G[m]+H[n]; max/min over k; BN stat partials -----
template<int COUT>
__global__ __launch_bounds__(256) void gather_kernel(
    const float* __restrict__ G, const float* __restrict__ H,
    const int* __restrict__ idx,
    float* __restrict__ ymax, float* __restrict__ ymin,
    float* __restrict__ psum, float* __restrict__ psumsq)
{
    constexpr int RPI = 256 / COUT;
    constexpr int NITER = 16 / RPI;
    int tid = threadIdx.x;
    int o = tid % COUT;
    int rsub = tid / COUT;
    int row0 = blockIdx.x * 16;       // grid = 512
    float s = 0.f, s2 = 0.f;
    for (int it = 0; it < NITER; ++it) {
        int r = row0 + it * RPI + rsub;
        int b = r >> 11;
        float h = H[(size_t)r * COUT + o];
        const int* ip = idx + (size_t)r * KK;
        float mx = -3.4e38f, mn = 3.4e38f;
#pragma unroll
        for (int j = 0; j < KK; ++j) {
            int m = ip[j];
            float g = G[((size_t)(b << 11) + m) * COUT + o];
            float y = g + h;
            mx = fmaxf(mx, y); mn = fminf(mn, y);
            s += y; s2 += y * y;
        }
        ymax[(size_t)r * COUT + o] = mx;
        ymin[(size_t)r * COUT + o] = mn;
    }
    __shared__ float ls[256], ls2[256];
    ls[tid] = s; ls2[tid] = s2;
    __syncthreads();
    for (int st = 128; st >= COUT; st >>= 1) {
        if (tid < st) { ls[tid] += ls[tid + st]; ls2[tid] += ls2[tid + st]; }
        __syncthreads();
    }
    if (tid < COUT) {
        psum[(size_t)blockIdx.x * COUT + tid]   = ls[tid];
        psumsq[(size_t)blockIdx.x * COUT + tid] = ls2[tid];
    }
}

// ---------------- finalize BN scale/shift: one block per channel ----------
__global__ __launch_bounds__(256) void bnscale_kernel(
    const float* __restrict__ psum, const float* __restrict__ psumsq,
    int nblk, int cout, float cnt,
    const float* __restrict__ gw, const float* __restrict__ bw,
    float* __restrict__ ss)
{
    int o = blockIdx.x;               // grid = cout
    int t = threadIdx.x;
    float s = 0.f, s2 = 0.f;
    for (int i = t; i < nblk; i += 256) {
        s  += psum[(size_t)i * cout + o];
        s2 += psumsq[(size_t)i * cout + o];
    }
    __shared__ float ls[256], ls2[256];
    ls[t] = s; ls2[t] = s2;
    __syncthreads();
    for (int st = 128; st > 0; st >>= 1) {
        if (t < st) { ls[t] += ls[t + st]; ls2[t] += ls2[t + st]; }
        __syncthreads();
    }
    if (t == 0) {
        float m = ls[0] / cnt;
        float v = ls2[0] / cnt - m * m;
        float sc = gw[o] / sqrtf(v + 1e-5f);
        float sh = bw[o] - m * sc;
        ss[o * 2] = sc; ss[o * 2 + 1] = sh;
    }
}

// ---------------- BN+LeakyReLU on max/min, elementwise (no fcn write) -----
__global__ __launch_bounds__(256) void apply_kernel(
    const float* __restrict__ ymax, const float* __restrict__ ymin,
    const float* __restrict__ ss, int coutShift, int choff,
    float* __restrict__ h512)
{
    size_t gid = (size_t)blockIdx.x * 256 + threadIdx.x;
    int o = (int)(gid & ((1u << coutShift) - 1));
    size_t r = gid >> coutShift;
    float sc = ss[o * 2], sh = ss[o * 2 + 1];
    float v = (sc >= 0.f) ? ymax[gid] : ymin[gid];
    float a = sc * v + sh;
    float act = (a > 0.f) ? a : NEG * a;
    h512[r * 512 + choff + o] = act;
}

// ---------------- BN+LeakyReLU + coalesced transposed fcn write -----------
template<int CO>
__global__ __launch_bounds__(256) void apply_t_kernel(
    const float* __restrict__ ymax, const float* __restrict__ ymin,
    const float* __restrict__ ss, int choff,
    float* __restrict__ h512, float* __restrict__ fcn)
{
    constexpr int TILES_O = CO >> 6;
    __shared__ float tile[64][65];
    int tr = blockIdx.x / TILES_O;    // row tile 0..127
    int to = blockIdx.x % TILES_O;
    int r0 = tr * 64, o0 = to * 64;
    int t = threadIdx.x;
    int lr = t >> 6;                  // 0..3
    int lo = t & 63;
    int o = o0 + lo;
    float sc = ss[o * 2], sh = ss[o * 2 + 1];
#pragma unroll
    for (int rr = 0; rr < 64; rr += 4) {
        int r = r0 + rr + lr;
        size_t gid = (size_t)r * CO + o;
        float v = (sc >= 0.f) ? ymax[gid] : ymin[gid];
        float a = sc * v + sh;
        float act = (a > 0.f) ? a : NEG * a;
        h512[(size_t)r * 512 + choff + o] = act;
        tile[rr + lr][lo] = act;
    }
    __syncthreads();
    int b = r0 >> 11;
    int n0 = r0 & 2047;
#pragma unroll
    for (int oo = 0; oo < 64; oo += 4) {
        fcn[((size_t)(b * CO + o0 + oo + lr)) * NN + n0 + lo] = tile[lo][oo + lr];
    }
}

// ---------- conv1d GEMM: 128x128 tile, 8x8 microtile (2x2 of 4x4) ---------
__global__ __launch_bounds__(256) void gemm5_kernel(
    const float* __restrict__ A, const float* __restrict__ W5,
    float* __restrict__ Y, float* __restrict__ psum, float* __restrict__ psumsq)
{
    __shared__ float As[16][132];
    __shared__ float Bs[16][132];
    int tid = threadIdx.x;
    int bm = blockIdx.x & 63;         // 64 row tiles
    int bn = blockIdx.x >> 6;         // 8 col tiles
    int row0 = bm * 128, col0 = bn * 128;
    int tx = tid & 15, ty = tid >> 4;
    int lr = tid >> 2;                // 0..63
    int lk = (tid & 3) * 4;

    const float* Ap0 = A  + (size_t)(row0 + lr)      * 512 + lk;
    const float* Ap1 = A  + (size_t)(row0 + 64 + lr) * 512 + lk;
    const float* Bp0 = W5 + (size_t)(col0 + lr)      * 512 + lk;
    const float* Bp1 = W5 + (size_t)(col0 + 64 + lr) * 512 + lk;

    float acc[8][8];
#pragma unroll
    for (int i = 0; i < 8; ++i)
#pragma unroll
        for (int j = 0; j < 8; ++j) acc[i][j] = 0.f;

    float4 av0 = *(const float4*)Ap0;
    float4 av1 = *(const float4*)Ap1;
    float4 bv0 = *(const float4*)Bp0;
    float4 bv1 = *(const float4*)Bp1;

    for (int k0 = 0; k0 < 512; k0 += 16) {
        As[lk + 0][lr] = av0.x; As[lk + 1][lr] = av0.y;
        As[lk + 2][lr] = av0.z; As[lk + 3][lr] = av0.w;
        As[lk + 0][64 + lr] = av1.x; As[lk + 1][64 + lr] = av1.y;
        As[lk + 2][64 + lr] = av1.z; As[lk + 3][64 + lr] = av1.w;
        Bs[lk + 0][lr] = bv0.x; Bs[lk + 1][lr] = bv0.y;
        Bs[lk + 2][lr] = bv0.z; Bs[lk + 3][lr] = bv0.w;
        Bs[lk + 0][64 + lr] = bv1.x; Bs[lk + 1][64 + lr] = bv1.y;
        Bs[lk + 2][64 + lr] = bv1.z; Bs[lk + 3][64 + lr] = bv1.w;
        __syncthreads();
        if (k0 + 16 < 512) {
            av0 = *(const float4*)(Ap0 + k0 + 16);
            av1 = *(const float4*)(Ap1 + k0 + 16);
            bv0 = *(const float4*)(Bp0 + k0 + 16);
            bv1 = *(const float4*)(Bp1 + k0 + 16);
        }
#pragma unroll
        for (int kk = 0; kk < 16; ++kk) {
            float4 a0 = *(const float4*)&As[kk][ty * 4];
            float4 a1 = *(const float4*)&As[kk][64 + ty * 4];
            float4 b0 = *(const float4*)&Bs[kk][tx * 4];
            float4 b1 = *(const float4*)&Bs[kk][64 + tx * 4];
            float ar[8] = {a0.x, a0.y, a0.z, a0.w, a1.x, a1.y, a1.z, a1.w};
            float br[8] = {b0.x, b0.y, b0.z, b0.w, b1.x, b1.y, b1.z, b1.w};
#pragma unroll
            for (int i = 0; i < 8; ++i)
#pragma unroll
                for (int j = 0; j < 8; ++j) acc[i][j] += ar[i] * br[j];
        }
        __syncthreads();
    }

#pragma unroll
    for (int ih = 0; ih < 2; ++ih) {
#pragma unroll
        for (int i = 0; i < 4; ++i) {
            int r = row0 + ih * 64 + ty * 4 + i;
            float4 v0 = {acc[ih*4+i][0], acc[ih*4+i][1], acc[ih*4+i][2], acc[ih*4+i][3]};
            float4 v1 = {acc[ih*4+i][4], acc[ih*4+i][5], acc[ih*4+i][6], acc[ih*4+i][7]};
            *(float4*)(Y + (size_t)r * 1024 + col0 + tx * 4) = v0;
            *(float4*)(Y + (size_t)r * 1024 + col0 + 64 + tx * 4) = v1;
        }
    }

    float* cs = &As[0][0];
    float* cq = &Bs[0][0];
#pragma unroll
    for (int jh = 0; jh < 2; ++jh) {
#pragma unroll
        for (int j = 0; j < 4; ++j) {
            float s = 0.f, q = 0.f;
#pragma unroll
            for (int i = 0; i < 8; ++i) {
                float v = acc[i][jh * 4 + j];
                s += v; q += v * v;
            }
            int col = jh * 64 + tx * 4 + j;
            cs[ty * 132 + col] = s;
            cq[ty * 132 + col] = q;
        }
    }
    __syncthreads();
    if (tid < 128) {
        float s = 0.f, q = 0.f;
#pragma unroll
        for (int y = 0; y < 16; ++y) { s += cs[y * 132 + tid]; q += cq[y * 132 + tid]; }
        psum[(size_t)bm * 1024 + col0 + tid]   = s;
        psumsq[(size_t)bm * 1024 + col0 + tid] = q;
    }
}

// ---------------- pool partials: BN+act, max & sum over 32-row chunks -----
__global__ __launch_bounds__(256) void pool_part_kernel(
    const float* __restrict__ Y, const float* __restrict__ ss,
    float* __restrict__ pmax, float* __restrict__ psum)
{
    int bid = blockIdx.x;             // 256 = B * 64 chunks
    int b = bid >> 6;
    int n0 = (bid & 63) * 32;
    int t = threadIdx.x;
    int o = t * 4;
    float4 sA = *(const float4*)(ss + o * 2);       // sc0 sh0 sc1 sh1
    float4 sB = *(const float4*)(ss + o * 2 + 4);   // sc2 sh2 sc3 sh3
    float4 mx = {-3.4e38f, -3.4e38f, -3.4e38f, -3.4e38f};
    float4 sm = {0.f, 0.f, 0.f, 0.f};
    const float* Yb = Y + ((size_t)b * NN + n0) * 1024 + o;
#pragma unroll 4
    for (int n = 0; n < 32; ++n) {
        float4 v = *(const float4*)(Yb + (size_t)n * 1024);
        float a0 = sA.x * v.x + sA.y; a0 = (a0 > 0.f) ? a0 : NEG * a0;
        float a1 = sA.z * v.y + sA.w; a1 = (a1 > 0.f) ? a1 : NEG * a1;
        float a2 = sB.x * v.z + sB.y; a2 = (a2 > 0.f) ? a2 : NEG * a2;
        float a3 = sB.z * v.w + sB.w; a3 = (a3 > 0.f) ? a3 : NEG * a3;
        mx.x = fmaxf(mx.x, a0); sm.x += a0;
        mx.y = fmaxf(mx.y, a1); sm.y += a1;
        mx.z = fmaxf(mx.z, a2); sm.z += a2;
        mx.w = fmaxf(mx.w, a3); sm.w += a3;
    }
    size_t po = (size_t)bid * 1024 + o;
    *(float4*)(pmax + po) = mx;
    *(float4*)(psum + po) = sm;
}

// ---------------- combine pool partials -> z (B,2048) ----------------
__global__ __launch_bounds__(256) void pool_comb_kernel(
    const float* __restrict__ pmax, const float* __restrict__ psum,
    float* __restrict__ z)
{
    int b = blockIdx.x;               // 4
    int t = threadIdx.x;
    int o = t * 4;
    float4 mx = {-3.4e38f, -3.4e38f, -3.4e38f, -3.4e38f};
    float4 sm = {0.f, 0.f, 0.f, 0.f};
    for (int ch = 0; ch < 64; ++ch) {
        size_t po = ((size_t)(b * 64 + ch)) * 1024 + o;
        float4 m = *(const float4*)(pmax + po);
        float4 s = *(const float4*)(psum + po);
        mx.x = fmaxf(mx.x, m.x); mx.y = fmaxf(mx.y, m.y);
        mx.z = fmaxf(mx.z, m.z); mx.w = fmaxf(mx.w, m.w);
        sm.x += s.x; sm.y += s.y; sm.z += s.z; sm.w += s.w;
    }
    *(float4*)(z + (size_t)b * 2048 + o) = mx;
    float4 mn = {sm.x * (1.f / 2048.f), sm.y * (1.f / 2048.f),
                 sm.z * (1.f / 2048.f), sm.w * (1.f / 2048.f)};
    *(float4*)(z + (size_t)b * 2048 + 1024 + o) = mn;
}

// ---------------- z @ lw1^T + lb1  -> z1 (4,256) ----------------
__global__ __launch_bounds__(64) void gemv1_kernel(
    const float* __restrict__ z, const float* __restrict__ lw1,
    const float* __restrict__ lb1, float* __restrict__ z1)
{
    int o = blockIdx.x;               // 256
    int lane = threadIdx.x;           // 64
    const float* wr = lw1 + (size_t)o * 2048;
    float a0 = 0.f, a1 = 0.f, a2 = 0.f, a3 = 0.f;
    for (int c = lane; c < 2048; c += 64) {
        float w = wr[c];
        a0 += z[c] * w; a1 += z[2048 + c] * w;
        a2 += z[4096 + c] * w; a3 += z[6144 + c] * w;
    }
#pragma unroll
    for (int off = 32; off > 0; off >>= 1) {
        a0 += __shfl_down(a0, off); a1 += __shfl_down(a1, off);
        a2 += __shfl_down(a2, off); a3 += __shfl_down(a3, off);
    }
    if (lane == 0) {
        float bias = lb1[o];
        z1[o] = a0 + bias; z1[256 + o] = a1 + bias;
        z1[512 + o] = a2 + bias; z1[768 + o] = a3 + bias;
    }
}

// ---------------- rest of head: z2, e, cluster q/xd ----------------
__global__ __launch_bounds__(1024) void head2_kernel(
    const float* __restrict__ z1,
    const float* __restrict__ lw2, const float* __restrict__ lb2,
    const float* __restrict__ lw3, const float* __restrict__ lb3,
    const float* __restrict__ cw,
    float* __restrict__ out, float* __restrict__ e_store, int which)
{
    __shared__ float z2s[4][64];
    __shared__ float es[4][10];
    __shared__ float qs[3200];
    __shared__ float dnm[4];
    int t = threadIdx.x;
    if (t < 256) {
        int b = t >> 6, o = t & 63;
        float acc = lb2[o];
        const float* wr = lw2 + (size_t)o * 256;
        const float* zr = z1 + b * 256;
        for (int c = 0; c < 256; ++c) acc += zr[c] * wr[c];
        z2s[b][o] = acc;
    }
    __syncthreads();
    if (t < 40) {
        int b = t / 10, o = t % 10;
        float acc = lb3[o];
        const float* wr = lw3 + o * 64;
        for (int c = 0; c < 64; ++c) acc += z2s[b][c] * wr[c];
        es[b][o] = acc;
        int eoff = (which == 0) ? EOFF0 : EOFF1;
        out[eoff + b * 10 + o] = acc;
        e_store[which * 40 + b * 10 + o] = acc;
    }
    __syncthreads();
    for (int p = t; p < 3200; p += 1024) {
        int b = p / 800, j = p % 800;
        float xd = 0.f;
        const float* cwr = cw + j * 10;
#pragma unroll
        for (int i = 0; i < 10; ++i) { float d = es[b][i] - cwr[i]; xd += d * d; }
        qs[p] = 1.0f / (1.0f + xd);
        if (which == 0) out[XDOFF + p] = xd;
    }
    __syncthreads();
    if (t < 4) {
        float s = 0.f;
        for (int j = 0; j < 800; ++j) s += qs[t * 800 + j];
        dnm[t] = s;
    }
    __syncthreads();
    int qoff = (which == 0) ? QOFF0 : QOFF1;
    for (int p = t; p < 3200; p += 1024) out[qoff + p] = qs[p] / dnm[p / 800];
}

// ---------------- pairwise distance of embeddings ----------------
__global__ void sim_kernel(const float* __restrict__ e_store, float* __restrict__ out)
{
    int t = threadIdx.x;
    if (t < 4) {
        float s = 0.f;
        for (int i = 0; i < 10; ++i) {
            float d = e_store[t * 10 + i] - e_store[40 + t * 10 + i] + 1e-6f;
            s += d * d;
        }
        out[t] = sqrtf(s);
    }
}

extern "C" void kernel_launch(void* const* d_in, const int* in_sizes, int n_in,
                              void* d_out, int out_size, void* d_ws, size_t ws_size,
                              hipStream_t stream)
{
    const float* x1  = (const float*)d_in[0];
    const float* x2  = (const float*)d_in[1];
    const float* w1  = (const float*)d_in[2];
    const float* g1  = (const float*)d_in[3];
    const float* b1  = (const float*)d_in[4];
    const float* w2  = (const float*)d_in[5];
    const float* g2  = (const float*)d_in[6];
    const float* b2  = (const float*)d_in[7];
    const float* w3  = (const float*)d_in[8];
    const float* g3  = (const float*)d_in[9];
    const float* b3  = (const float*)d_in[10];
    const float* w4  = (const float*)d_in[11];
    const float* g4  = (const float*)d_in[12];
    const float* b4  = (const float*)d_in[13];
    const float* w5  = (const float*)d_in[14];
    const float* g5  = (const float*)d_in[15];
    const float* b5  = (const float*)d_in[16];
    const float* lw1 = (const float*)d_in[17];
    const float* lb1 = (const float*)d_in[18];
    const float* lw2 = (const float*)d_in[19];
    const float* lb2 = (const float*)d_in[20];
    const float* lw3 = (const float*)d_in[21];
    const float* lb3 = (const float*)d_in[22];
    const float* cw  = (const float*)d_in[23];
    float* out = (float*)d_out;

    float* ws   = (float*)d_ws;
    float* h512 = ws;                      // B*N*512 = 4194304
    float* G    = h512 + 4194304;          // 2097152 (B*N*256 max)
    float* Hb   = G + 2097152;             // 2097152
    float* ymax = Hb + 2097152;            // 2097152
    float* ymin = ymax + 2097152;          // 2097152
    float* y5   = G;                       // alias: B*N*1024 = 8388608 = G..ymin
    float* fcn  = ymin + 2097152;          // 1048576 (B*128*N max)
    float* fnc1 = fcn + 1048576;           // 32768 (B*N*3 padded)
    float* xx   = fnc1 + 32768;            // 8192
    float* psum = xx + 8192;               // 131072 (512*256)
    float* psq  = psum + 131072;           // 131072
    float* ss   = psq + 131072;            // 2048
    float* p5s  = ss + 2048;               // 262144 (stats: 64*1024; pool: 256*1024)
    float* p5q  = p5s + 262144;            // 262144
    float* ss5  = p5q + 262144;            // 2048
    float* z    = ss5 + 2048;              // 8192
    float* z1   = z + 8192;                // 1024
    float* est  = z1 + 1024;               // 128
    int*   idx  = (int*)(est + 128);       // B*N*20 ints

    for (int which = 0; which < 2; ++which) {
        const float* xin = which ? x2 : x1;
        // ---- layer 1 (C=3 -> 64, choff 0)
        transpose_x_kernel<<<32, 256, 0, stream>>>(xin, fnc1, xx);
        knn_kernel<3><<<1024, 512, 0, stream>>>(xin, fnc1, 3, 0, xx, idx);
        gemm_gh_kernel<3, 64><<<1024, 256, 0, stream>>>(fnc1, 3, 0, w1, G, Hb);
        gather_kernel<64><<<512, 256, 0, stream>>>(G, Hb, idx, ymax, ymin, psum, psq);
        bnscale_kernel<<<64, 256, 0, stream>>>(psum, psq, 512, 64, 163840.f, g1, b1, ss);
        apply_t_kernel<64><<<128, 256, 0, stream>>>(ymax, ymin, ss, 0, h512, fcn);
        // ---- layer 2 (C=64 -> 64, choff 64)
        norms_kernel<<<32, 256, 0, stream>>>(h512, 0, 64, xx);
        knn_kernel<64><<<1024, 512, 0, stream>>>(fcn, h512, 512, 0, xx, idx);
        gemm_gh_kernel<64, 64><<<1024, 256, 0, stream>>>(h512, 512, 0, w2, G, Hb);
        gather_kernel<64><<<512, 256, 0, stream>>>(G, Hb, idx, ymax, ymin, psum, psq);
        bnscale_kernel<<<64, 256, 0, stream>>>(psum, psq, 512, 64, 163840.f, g2, b2, ss);
        apply_t_kernel<64><<<128, 256, 0, stream>>>(ymax, ymin, ss, 64, h512, fcn);
        // ---- layer 3 (C=64 -> 128, choff 128)
        norms_kernel<<<32, 256, 0, stream>>>(h512, 64, 64, xx);
        knn_kernel<64><<<1024, 512, 0, stream>>>(fcn, h512, 512, 64, xx, idx);
        gemm_gh_kernel<64, 128><<<1024, 256, 0, stream>>>(h512, 512, 64, w3, G, Hb);
        gather_kernel<128><<<512, 256, 0, stream>>>(G, Hb, idx, ymax, ymin, psum, psq);
        bnscale_kernel<<<128, 256, 0, stream>>>(psum, psq, 512, 128, 163840.f, g3, b3, ss);
        apply_t_kernel<128><<<256, 256, 0, stream>>>(ymax, ymin, ss, 128, h512, fcn);
        // ---- layer 4 (C=128 -> 256, choff 256)
        norms_kernel<<<32, 256, 0, stream>>>(h512, 128, 128, xx);
        knn_kernel<128><<<1024, 512, 0, stream>>>(fcn, h512, 512, 128, xx, idx);
        gemm_gh_kernel<128, 256><<<1024, 256, 0, stream>>>(h512, 512, 128, w4, G, Hb);
        gather_kernel<256><<<512, 256, 0, stream>>>(G, Hb, idx, ymax, ymin, psum, psq);
        bnscale_kernel<<<256, 256, 0, stream>>>(psum, psq, 512, 256, 163840.f, g4, b4, ss);
        apply_kernel<<<8192, 256, 0, stream>>>(ymax, ymin, ss, 8, 256, h512);
        // ---- conv1d (512 -> 1024) + fused stats + BN + act + max/mean pool
        gemm5_kernel<<<512, 256, 0, stream>>>(h512, w5, y5, p5s, p5q);
        bnscale_kernel<<<1024, 256, 0, stream>>>(p5s, p5q, 64, 1024, 8192.f, g5, b5, ss5);
        pool_part_kernel<<<256, 256, 0, stream>>>(y5, ss5, p5s, p5q);
        pool_comb_kernel<<<4, 256, 0, stream>>>(p5s, p5q, z);
        // ---- head
        gemv1_kernel<<<256, 64, 0, stream>>>(z, lw1, lb1, z1);
        head2_kernel<<<1, 1024, 0, stream>>>(z1, lw2, lb2, lw3, lb3, cw, out, est, which);
    }
    sim_kernel<<<1, 64, 0, stream>>>(est, out);
}

// Round 11
// 1447.353 us; speedup vs baseline: 1.0338x; 1.0338x over previous
//
#include <hip/hip_runtime.h>
#include <math.h>

#define BB 4
#define NN 2048
#define KK 20
#define NEG 0.2f

// d_out layout: sim(4) q1(3200) q2(3200) e1(40) e2(40) xd1(3200) = 9684
#define QOFF0 4
#define QOFF1 3204
#define EOFF0 6404
#define EOFF1 6444
#define XDOFF 6484

// ---------------- transpose x (B,3,N) -> (B,N,3) + row norms ----------------
__global__ __launch_bounds__(256) void transpose_x_kernel(
    const float* __restrict__ x, float* __restrict__ fnc, float* __restrict__ xx)
{
    int gid = blockIdx.x * 256 + threadIdx.x;   // B*N = 8192
    int b = gid >> 11, n = gid & 2047;
    float s = 0.f;
#pragma unroll
    for (int c = 0; c < 3; ++c) {
        float v = x[((size_t)b * 3 + c) * NN + n];
        fnc[(size_t)gid * 3 + c] = v;
        s += v * v;
    }
    xx[gid] = s;
}

// ---------------- row norms of a h512 channel slice ----------------
__global__ __launch_bounds__(256) void norms_kernel(
    const float* __restrict__ h512, int choff, int C, float* __restrict__ xx)
{
    int gid = blockIdx.x * 256 + threadIdx.x;   // 8192
    const float* p = h512 + (size_t)gid * 512 + choff;
    float s = 0.f;
    for (int c = 0; c < C; ++c) { float v = p[c]; s += v * v; }
    xx[gid] = s;
}

// ---- DPP argmax step: combine with neighbor moved by CTRL (VALU, no LDS) ----
template<int CTRL>
__device__ __forceinline__ void dpp_step(float& v, int& i)
{
    int vi = __float_as_int(v);
    int nv = __builtin_amdgcn_update_dpp(vi, vi, CTRL, 0xf, 0xf, false);
    int ni = __builtin_amdgcn_update_dpp(i,  i,  CTRL, 0xf, 0xf, false);
    float nvf = __int_as_float(nv);
    if (nvf > v || (nvf == v && ni < i)) { v = nvf; i = ni; }
}

// ---------------- fused pairwise-dot + top-20 ----------------
// Dot phase: R8 structure (c-groups of 4, next-group register prefetch,
// centers via wave-uniform s_load_dwordx4, XCD-swizzled batch).
// Select: row pulled ONCE into 32 registers; consumed tracked by per-lane
// bitmask; 20-iteration loop is pure VALU (DPP argmax) - no LDS ops.
template<int C>
__global__ __launch_bounds__(512, 4) void knn_kernel(
    const float* __restrict__ fcn,   // (B,C,N)
    const float* __restrict__ fnc,   // rows of length ncs, center vectors at +choff
    int ncs, int choff,
    const float* __restrict__ xx, int* __restrict__ idxout)
{
    __shared__ float sbuf[8][NN];    // 64 KB
    int tid = threadIdx.x;
    int bid = blockIdx.x;            // 1024
    int b   = bid & 3;
    int n0  = (((bid >> 3) << 1) | ((bid >> 2) & 1)) * 8;   // covers 0..2047 per batch

    const float* fb = fcn + (size_t)b * C * NN;
    const float* xb = xx + b * NN;
    const float* cbase = fnc + (size_t)(b * NN + n0) * ncs + choff;

    float a0[8], a1[8], a2[8], a3[8];
#pragma unroll
    for (int r = 0; r < 8; ++r) { a0[r] = 0.f; a1[r] = 0.f; a2[r] = 0.f; a3[r] = 0.f; }

    const float* fp = fb + 4 * tid;

    if constexpr (C % 4 == 0) {
        float4 buf[4];
#pragma unroll
        for (int q = 0; q < 4; ++q) buf[q] = *(const float4*)(fp + (size_t)q * NN);
        for (int cg = 0; cg < C; cg += 4) {
            float4 nxt[4];
            if (cg + 4 < C) {
#pragma unroll
                for (int q = 0; q < 4; ++q)
                    nxt[q] = *(const float4*)(fp + (size_t)(cg + 4 + q) * NN);
            } else {
#pragma unroll
                for (int q = 0; q < 4; ++q) nxt[q] = buf[q];
            }
            float4 cv[8];
#pragma unroll
            for (int r = 0; r < 8; ++r)
                cv[r] = *(const float4*)(cbase + (size_t)r * ncs + cg);  // uniform -> s_load_dwordx4
#pragma unroll
            for (int r = 0; r < 8; ++r) {
                a0[r] += cv[r].x * buf[0].x; a1[r] += cv[r].x * buf[0].y;
                a2[r] += cv[r].x * buf[0].z; a3[r] += cv[r].x * buf[0].w;
                a0[r] += cv[r].y * buf[1].x; a1[r] += cv[r].y * buf[1].y;
                a2[r] += cv[r].y * buf[1].z; a3[r] += cv[r].y * buf[1].w;
                a0[r] += cv[r].z * buf[2].x; a1[r] += cv[r].z * buf[2].y;
                a2[r] += cv[r].z * buf[2].z; a3[r] += cv[r].z * buf[2].w;
                a0[r] += cv[r].w * buf[3].x; a1[r] += cv[r].w * buf[3].y;
                a2[r] += cv[r].w * buf[3].z; a3[r] += cv[r].w * buf[3].w;
            }
#pragma unroll
            for (int q = 0; q < 4; ++q) buf[q] = nxt[q];
        }
    } else {
        for (int c = 0; c < C; ++c) {
            float cr[8];
#pragma unroll
            for (int r = 0; r < 8; ++r) cr[r] = cbase[(size_t)r * ncs + c];
            float4 v = *(const float4*)(fp + (size_t)c * NN);
#pragma unroll
            for (int r = 0; r < 8; ++r) {
                a0[r] += cr[r] * v.x; a1[r] += cr[r] * v.y;
                a2[r] += cr[r] * v.z; a3[r] += cr[r] * v.w;
            }
        }
    }
    {
        float4 xm = *(const float4*)(xb + 4 * tid);
#pragma unroll
        for (int r = 0; r < 8; ++r) {
            float4 sv = {2.f * a0[r] - xm.x, 2.f * a1[r] - xm.y,
                         2.f * a2[r] - xm.z, 2.f * a3[r] - xm.w};
            *(float4*)&sbuf[r][4 * tid] = sv;
        }
    }
    __syncthreads();

    // ---- select phase: wave w (0..7) handles row w; register-resident
    int w = tid >> 6, lane = tid & 63;
    float* sb = sbuf[w];
    int* op = idxout + (size_t)(b * NN + n0 + w) * KK;
    const float NINF = -3.4e38f;

    // pull row into registers: rv[j] = sb[lane + 64*j] (conflict-free, once)
    float rv[32];
#pragma unroll
    for (int j = 0; j < 32; ++j) rv[j] = sb[lane + (j << 6)];

    unsigned consumed = 0u;   // bit j set => element j consumed by this lane

    // initial per-lane top-2 (ascending j -> earliest kept on equal)
    float v1 = NINF, v2 = NINF; int j1 = -1, j2 = -1;
#pragma unroll
    for (int j = 0; j < 32; ++j) {
        float vv = rv[j];
        if (vv > v1) { v2 = v1; j2 = j1; v1 = vv; j1 = j; }
        else if (vv > v2) { v2 = vv; j2 = j; }
    }
    int i1 = (j1 < 0) ? -1 : lane + (j1 << 6);
    int i2 = (j2 < 0) ? -1 : lane + (j2 << 6);

    for (int it = 0; it < KK; ++it) {
        float bv = v1; int bi = i1;
        dpp_step<0x111>(bv, bi);   // row_shr:1
        dpp_step<0x112>(bv, bi);   // row_shr:2
        dpp_step<0x114>(bv, bi);   // row_shr:4
        dpp_step<0x118>(bv, bi);   // row_shr:8
        dpp_step<0x142>(bv, bi);   // row_bcast:15
        dpp_step<0x143>(bv, bi);   // row_bcast:31 -> lane 63 holds argmax
        int win = __builtin_amdgcn_readlane(bi, 63);
        if (lane == 0) op[it] = win;
        if (i1 == win) {           // owner lane consumes (win%64 == lane)
            consumed |= 1u << j1;
            v1 = v2; i1 = i2; j1 = j2;
            v2 = NINF; i2 = -1; j2 = -1;
        }
        if (__any(v1 == NINF)) {   // rare: a lane exhausted its cached top-2
            if (v1 == NINF) {
                v1 = NINF; v2 = NINF; j1 = -1; j2 = -1;
#pragma unroll
                for (int j = 0; j < 32; ++j) {
                    if (!(consumed & (1u << j))) {
                        float vv = rv[j];
                        if (vv > v1) { v2 = v1; j2 = j1; v1 = vv; j1 = j; }
                        else if (vv > v2) { v2 = vv; j2 = j; }
                    }
                }
                i1 = (j1 < 0) ? -1 : lane + (j1 << 6);
                i2 = (j2 < 0) ? -1 : lane + (j2 << 6);
            }
        }
    }
}

// ---------------- G = F*W1^T, H = F*(W2-W1)^T  (out layout (B*N, COUT)) ----
template<int C, int COUT>
__global__ __launch_bounds__(256) void gemm_gh_kernel(
    const float* __restrict__ fnc, int ncs, int choff,
    const float* __restrict__ W,     // (COUT, 2C)
    float* __restrict__ G, float* __restrict__ H)
{
    constexpr int GROUPS = 256 / COUT;
    constexpr int RPT = 8 / GROUPS;
    __shared__ float Fs[8][C];
    int tid = threadIdx.x;
    int row0 = blockIdx.x * 8;        // grid = B*N/8 = 1024
    for (int i = tid; i < 8 * C; i += 256) {
        int r = i / C, c = i % C;
        Fs[r][c] = fnc[(size_t)(row0 + r) * ncs + choff + c];
    }
    __syncthreads();
    int o = tid % COUT;
    int r0 = (tid / COUT) * RPT;
    float g[RPT], h[RPT];
#pragma unroll
    for (int r = 0; r < RPT; ++r) { g[r] = 0.f; h[r] = 0.f; }
    const float* wr = W + (size_t)o * 2 * C;
    for (int c = 0; c < C; ++c) {
        float w1 = wr[c], wd = wr[C + c] - w1;
#pragma unroll
        for (int r = 0; r < RPT; ++r) {
            float f = Fs[r0 + r][c];
            g[r] += f * w1; h[r] += f * wd;
        }
    }
#pragma unroll
    for (int r = 0; r < RPT; ++r) {
        size_t rr = (size_t)(row0 + r0 + r) * COUT + o;
        G[rr] = g[r]; H[rr] = h[r];
    }
}

// ---------------- gather y=G[m]+H[n]; max/min over k; BN stat partials -----
template<int COUT>
__global__ __launch_bounds__(256) void gather_kernel(
    const float* __restrict__ G, const float* __restrict__ H,
    const int* __restrict__ idx,
    float* __restrict__ ymax, float* __restrict__ ymin,
    float* __restrict__ psum, float* __restrict__ psumsq)
{
    constexpr int RPI = 256 / COUT;
    constexpr int NITER = 16 / RPI;
    int tid = threadIdx.x;
    int o = tid % COUT;
    int rsub = tid / COUT;
    int row0 = blockIdx.x * 16;       // grid = 512
    float s = 0.f, s2 = 0.f;
    for (int it = 0; it < NITER; ++it) {
        int r = row0 + it * RPI + rsub;
        int b = r >> 11;
        float h = H[(size_t)r * COUT + o];
        const int* ip = idx + (size_t)r * KK;
        float mx = -3.4e38f, mn = 3.4e38f;
#pragma unroll
        for (int j = 0; j < KK; ++j) {
            int m = ip[j];
            float g = G[((size_t)(b << 11) + m) * COUT + o];
            float y = g + h;
            mx = fmaxf(mx, y); mn = fminf(mn, y);
            s += y; s2 += y * y;
        }
        ymax[(size_t)r * COUT + o] = mx;
        ymin[(size_t)r * COUT + o] = mn;
    }
    __shared__ float ls[256], ls2[256];
    ls[tid] = s; ls2[tid] = s2;
    __syncthreads();
    for (int st = 128; st >= COUT; st >>= 1) {
        if (tid < st) { ls[tid] += ls[tid + st]; ls2[tid] += ls2[tid + st]; }
        __syncthreads();
    }
    if (tid < COUT) {
        psum[(size_t)blockIdx.x * COUT + tid]   = ls[tid];
        psumsq[(size_t)blockIdx.x * COUT + tid] = ls2[tid];
    }
}

// ---------------- finalize BN scale/shift: one block per channel ----------
__global__ __launch_bounds__(256) void bnscale_kernel(
    const float* __restrict__ psum, const float* __restrict__ psumsq,
    int nblk, int cout, float cnt,
    const float* __restrict__ gw, const float* __restrict__ bw,
    float* __restrict__ ss)
{
    int o = blockIdx.x;               // grid = cout
    int t = threadIdx.x;
    float s = 0.f, s2 = 0.f;
    for (int i = t; i < nblk; i += 256) {
        s  += psum[(size_t)i * cout + o];
        s2 += psumsq[(size_t)i * cout + o];
    }
    __shared__ float ls[256], ls2[256];
    ls[t] = s; ls2[t] = s2;
    __syncthreads();
    for (int st = 128; st > 0; st >>= 1) {
        if (t < st) { ls[t] += ls[t + st]; ls2[t] += ls2[t + st]; }
        __syncthreads();
    }
    if (t == 0) {
        float m = ls[0] / cnt;
        float v = ls2[0] / cnt - m * m;
        float sc = gw[o] / sqrtf(v + 1e-5f);
        float sh = bw[o] - m * sc;
        ss[o * 2] = sc; ss[o * 2 + 1] = sh;
    }
}

// ---------------- BN+LeakyReLU on max/min, elementwise (no fcn write) -----
__global__ __launch_bounds__(256) void apply_kernel(
    const float* __restrict__ ymax, const float* __restrict__ ymin,
    const float* __restrict__ ss, int coutShift, int choff,
    float* __restrict__ h512)
{
    size_t gid = (size_t)blockIdx.x * 256 + threadIdx.x;
    int o = (int)(gid & ((1u << coutShift) - 1));
    size_t r = gid >> coutShift;
    float sc = ss[o * 2], sh = ss[o * 2 + 1];
    float v = (sc >= 0.f) ? ymax[gid] : ymin[gid];
    float a = sc * v + sh;
    float act = (a > 0.f) ? a : NEG * a;
    h512[r * 512 + choff + o] = act;
}

// ---------------- BN+LeakyReLU + coalesced transposed fcn write -----------
template<int CO>
__global__ __launch_bounds__(256) void apply_t_kernel(
    const float* __restrict__ ymax, const float* __restrict__ ymin,
    const float* __restrict__ ss, int choff,
    float* __restrict__ h512, float* __restrict__ fcn)
{
    constexpr int TILES_O = CO >> 6;
    __shared__ float tile[64][65];
    int tr = blockIdx.x / TILES_O;    // row tile 0..127
    int to = blockIdx.x % TILES_O;
    int r0 = tr * 64, o0 = to * 64;
    int t = threadIdx.x;
    int lr = t >> 6;                  // 0..3
    int lo = t & 63;
    int o = o0 + lo;
    float sc = ss[o * 2], sh = ss[o * 2 + 1];
#pragma unroll
    for (int rr = 0; rr < 64; rr += 4) {
        int r = r0 + rr + lr;
        size_t gid = (size_t)r * CO + o;
        float v = (sc >= 0.f) ? ymax[gid] : ymin[gid];
        float a = sc * v + sh;
        float act = (a > 0.f) ? a : NEG * a;
        h512[(size_t)r * 512 + choff + o] = act;
        tile[rr + lr][lo] = act;
    }
    __syncthreads();
    int b = r0 >> 11;
    int n0 = r0 & 2047;
#pragma unroll
    for (int oo = 0; oo < 64; oo += 4) {
        fcn[((size_t)(b * CO + o0 + oo + lr)) * NN + n0 + lo] = tile[lo][oo + lr];
    }
}

// ---------- conv1d GEMM: 128x128 tile, 8x8 microtile (2x2 of 4x4) ---------
__global__ __launch_bounds__(256) void gemm5_kernel(
    const float* __restrict__ A, const float* __restrict__ W5,
    float* __restrict__ Y, float* __restrict__ psum, float* __restrict__ psumsq)
{
    __shared__ float As[16][132];
    __shared__ float Bs[16][132];
    int tid = threadIdx.x;
    int bm = blockIdx.x & 63;         // 64 row tiles
    int bn = blockIdx.x >> 6;         // 8 col tiles
    int row0 = bm * 128, col0 = bn * 128;
    int tx = tid & 15, ty = tid >> 4;
    int lr = tid >> 2;                // 0..63
    int lk = (tid & 3) * 4;

    const float* Ap0 = A  + (size_t)(row0 + lr)      * 512 + lk;
    const float* Ap1 = A  + (size_t)(row0 + 64 + lr) * 512 + lk;
    const float* Bp0 = W5 + (size_t)(col0 + lr)      * 512 + lk;
    const float* Bp1 = W5 + (size_t)(col0 + 64 + lr) * 512 + lk;

    float acc[8][8];
#pragma unroll
    for (int i = 0; i < 8; ++i)
#pragma unroll
        for (int j = 0; j < 8; ++j) acc[i][j] = 0.f;

    float4 av0 = *(const float4*)Ap0;
    float4 av1 = *(const float4*)Ap1;
    float4 bv0 = *(const float4*)Bp0;
    float4 bv1 = *(const float4*)Bp1;

    for (int k0 = 0; k0 < 512; k0 += 16) {
        As[lk + 0][lr] = av0.x; As[lk + 1][lr] = av0.y;
        As[lk + 2][lr] = av0.z; As[lk + 3][lr] = av0.w;
        As[lk + 0][64 + lr] = av1.x; As[lk + 1][64 + lr] = av1.y;
        As[lk + 2][64 + lr] = av1.z; As[lk + 3][64 + lr] = av1.w;
        Bs[lk + 0][lr] = bv0.x; Bs[lk + 1][lr] = bv0.y;
        Bs[lk + 2][lr] = bv0.z; Bs[lk + 3][lr] = bv0.w;
        Bs[lk + 0][64 + lr] = bv1.x; Bs[lk + 1][64 + lr] = bv1.y;
        Bs[lk + 2][64 + lr] = bv1.z; Bs[lk + 3][64 + lr] = bv1.w;
        __syncthreads();
        if (k0 + 16 < 512) {
            av0 = *(const float4*)(Ap0 + k0 + 16);
            av1 = *(const float4*)(Ap1 + k0 + 16);
            bv0 = *(const float4*)(Bp0 + k0 + 16);
            bv1 = *(const float4*)(Bp1 + k0 + 16);
        }
#pragma unroll
        for (int kk = 0; kk < 16; ++kk) {
            float4 a0 = *(const float4*)&As[kk][ty * 4];
            float4 a1 = *(const float4*)&As[kk][64 + ty * 4];
            float4 b0 = *(const float4*)&Bs[kk][tx * 4];
            float4 b1 = *(const float4*)&Bs[kk][64 + tx * 4];
            float ar[8] = {a0.x, a0.y, a0.z, a0.w, a1.x, a1.y, a1.z, a1.w};
            float br[8] = {b0.x, b0.y, b0.z, b0.w, b1.x, b1.y, b1.z, b1.w};
#pragma unroll
            for (int i = 0; i < 8; ++i)
#pragma unroll
                for (int j = 0; j < 8; ++j) acc[i][j] += ar[i] * br[j];
        }
        __syncthreads();
    }

#pragma unroll
    for (int ih = 0; ih < 2; ++ih) {
#pragma unroll
        for (int i = 0; i < 4; ++i) {
            int r = row0 + ih * 64 + ty * 4 + i;
            float4 v0 = {acc[ih*4+i][0], acc[ih*4+i][1], acc[ih*4+i][2], acc[ih*4+i][3]};
            float4 v1 = {acc[ih*4+i][4], acc[ih*4+i][5], acc[ih*4+i][6], acc[ih*4+i][7]};
            *(float4*)(Y + (size_t)r * 1024 + col0 + tx * 4) = v0;
            *(float4*)(Y + (size_t)r * 1024 + col0 + 64 + tx * 4) = v1;
        }
    }

    float* cs = &As[0][0];
    float* cq = &Bs[0][0];
#pragma unroll
    for (int jh = 0; jh < 2; ++jh) {
#pragma unroll
        for (int j = 0; j < 4; ++j) {
            float s = 0.f, q = 0.f;
#pragma unroll
            for (int i = 0; i < 8; ++i) {
                float v = acc[i][jh * 4 + j];
                s += v; q += v * v;
            }
            int col = jh * 64 + tx * 4 + j;
            cs[ty * 132 + col] = s;
            cq[ty * 132 + col] = q;
        }
    }
    __syncthreads();
    if (tid < 128) {
        float s = 0.f, q = 0.f;
#pragma unroll
        for (int y = 0; y < 16; ++y) { s += cs[y * 132 + tid]; q += cq[y * 132 + tid]; }
        psum[(size_t)bm * 1024 + col0 + tid]   = s;
        psumsq[(size_t)bm * 1024 + col0 + tid] = q;
    }
}

// ---------------- pool partials: BN+act, max & sum over 32-row chunks -----
__global__ __launch_bounds__(256) void pool_part_kernel(
    const float* __restrict__ Y, const float* __restrict__ ss,
    float* __restrict__ pmax, float* __restrict__ psum)
{
    int bid = blockIdx.x;             // 256 = B * 64 chunks
    int b = bid >> 6;
    int n0 = (bid & 63) * 32;
    int t = threadIdx.x;
    int o = t * 4;
    float4 sA = *(const float4*)(ss + o * 2);       // sc0 sh0 sc1 sh1
    float4 sB = *(const float4*)(ss + o * 2 + 4);   // sc2 sh2 sc3 sh3
    float4 mx = {-3.4e38f, -3.4e38f, -3.4e38f, -3.4e38f};
    float4 sm = {0.f, 0.f, 0.f, 0.f};
    const float* Yb = Y + ((size_t)b * NN + n0) * 1024 + o;
#pragma unroll 4
    for (int n = 0; n < 32; ++n) {
        float4 v = *(const float4*)(Yb + (size_t)n * 1024);
        float a0 = sA.x * v.x + sA.y; a0 = (a0 > 0.f) ? a0 : NEG * a0;
        float a1 = sA.z * v.y + sA.w; a1 = (a1 > 0.f) ? a1 : NEG * a1;
        float a2 = sB.x * v.z + sB.y; a2 = (a2 > 0.f) ? a2 : NEG * a2;
        float a3 = sB.z * v.w + sB.w; a3 = (a3 > 0.f) ? a3 : NEG * a3;
        mx.x = fmaxf(mx.x, a0); sm.x += a0;
        mx.y = fmaxf(mx.y, a1); sm.y += a1;
        mx.z = fmaxf(mx.z, a2); sm.z += a2;
        mx.w = fmaxf(mx.w, a3); sm.w += a3;
    }
    size_t po = (size_t)bid * 1024 + o;
    *(float4*)(pmax + po) = mx;
    *(float4*)(psum + po) = sm;
}

// ---------------- combine pool partials -> z (B,2048) ----------------
__global__ __launch_bounds__(256) void pool_comb_kernel(
    const float* __restrict__ pmax, const float* __restrict__ psum,
    float* __restrict__ z)
{
    int b = blockIdx.x;               // 4
    int t = threadIdx.x;
    int o = t * 4;
    float4 mx = {-3.4e38f, -3.4e38f, -3.4e38f, -3.4e38f};
    float4 sm = {0.f, 0.f, 0.f, 0.f};
    for (int ch = 0; ch < 64; ++ch) {
        size_t po = ((size_t)(b * 64 + ch)) * 1024 + o;
        float4 m = *(const float4*)(pmax + po);
        float4 s = *(const float4*)(psum + po);
        mx.x = fmaxf(mx.x, m.x); mx.y = fmaxf(mx.y, m.y);
        mx.z = fmaxf(mx.z, m.z); mx.w = fmaxf(mx.w, m.w);
        sm.x += s.x; sm.y += s.y; sm.z += s.z; sm.w += s.w;
    }
    *(float4*)(z + (size_t)b * 2048 + o) = mx;
    float4 mn = {sm.x * (1.f / 2048.f), sm.y * (1.f / 2048.f),
                 sm.z * (1.f / 2048.f), sm.w * (1.f / 2048.f)};
    *(float4*)(z + (size_t)b * 2048 + 1024 + o) = mn;
}

// ---------------- z @ lw1^T + lb1  -> z1 (4,256) ----------------
__global__ __launch_bounds__(64) void gemv1_kernel(
    const float* __restrict__ z, const float* __restrict__ lw1,
    const float* __restrict__ lb1, float* __restrict__ z1)
{
    int o = blockIdx.x;               // 256
    int lane = threadIdx.x;           // 64
    const float* wr = lw1 + (size_t)o * 2048;
    float a0 = 0.f, a1 = 0.f, a2 = 0.f, a3 = 0.f;
    for (int c = lane; c < 2048; c += 64) {
        float w = wr[c];
        a0 += z[c] * w; a1 += z[2048 + c] * w;
        a2 += z[4096 + c] * w; a3 += z[6144 + c] * w;
    }
#pragma unroll
    for (int off = 32; off > 0; off >>= 1) {
        a0 += __shfl_down(a0, off); a1 += __shfl_down(a1, off);
        a2 += __shfl_down(a2, off); a3 += __shfl_down(a3, off);
    }
    if (lane == 0) {
        float bias = lb1[o];
        z1[o] = a0 + bias; z1[256 + o] = a1 + bias;
        z1[512 + o] = a2 + bias; z1[768 + o] = a3 + bias;
    }
}

// ---------------- rest of head: z2, e, cluster q/xd ----------------
__global__ __launch_bounds__(1024) void head2_kernel(
    const float* __restrict__ z1,
    const float* __restrict__ lw2, const float* __restrict__ lb2,
    const float* __restrict__ lw3, const float* __restrict__ lb3,
    const float* __restrict__ cw,
    float* __restrict__ out, float* __restrict__ e_store, int which)
{
    __shared__ float z2s[4][64];
    __shared__ float es[4][10];
    __shared__ float qs[3200];
    __shared__ float dnm[4];
    int t = threadIdx.x;
    if (t < 256) {
        int b = t >> 6, o = t & 63;
        float acc = lb2[o];
        const float* wr = lw2 + (size_t)o * 256;
        const float* zr = z1 + b * 256;
        for (int c = 0; c < 256; ++c) acc += zr[c] * wr[c];
        z2s[b][o] = acc;
    }
    __syncthreads();
    if (t < 40) {
        int b = t / 10, o = t % 10;
        float acc = lb3[o];
        const float* wr = lw3 + o * 64;
        for (int c = 0; c < 64; ++c) acc += z2s[b][c] * wr[c];
        es[b][o] = acc;
        int eoff = (which == 0) ? EOFF0 : EOFF1;
        out[eoff + b * 10 + o] = acc;
        e_store[which * 40 + b * 10 + o] = acc;
    }
    __syncthreads();
    for (int p = t; p < 3200; p += 1024) {
        int b = p / 800, j = p % 800;
        float xd = 0.f;
        const float* cwr = cw + j * 10;
#pragma unroll
        for (int i = 0; i < 10; ++i) { float d = es[b][i] - cwr[i]; xd += d * d; }
        qs[p] = 1.0f / (1.0f + xd);
        if (which == 0) out[XDOFF + p] = xd;
    }
    __syncthreads();
    if (t < 4) {
        float s = 0.f;
        for (int j = 0; j < 800; ++j) s += qs[t * 800 + j];
        dnm[t] = s;
    }
    __syncthreads();
    int qoff = (which == 0) ? QOFF0 : QOFF1;
    for (int p = t; p < 3200; p += 1024) out[qoff + p] = qs[p] / dnm[p / 800];
}

// ---------------- pairwise distance of embeddings ----------------
__global__ void sim_kernel(const float* __restrict__ e_store, float* __restrict__ out)
{
    int t = threadIdx.x;
    if (t < 4) {
        float s = 0.f;
        for (int i = 0; i < 10; ++i) {
            float d = e_store[t * 10 + i] - e_store[40 + t * 10 + i] + 1e-6f;
            s += d * d;
        }
        out[t] = sqrtf(s);
    }
}

extern "C" void kernel_launch(void* const* d_in, const int* in_sizes, int n_in,
                              void* d_out, int out_size, void* d_ws, size_t ws_size,
                              hipStream_t stream)
{
    const float* x1  = (const float*)d_in[0];
    const float* x2  = (const float*)d_in[1];
    const float* w1  = (const float*)d_in[2];
    const float* g1  = (const float*)d_in[3];
    const float* b1  = (const float*)d_in[4];
    const float* w2  = (const float*)d_in[5];
    const float* g2  = (const float*)d_in[6];
    const float* b2  = (const float*)d_in[7];
    const float* w3  = (const float*)d_in[8];
    const float* g3  = (const float*)d_in[9];
    const float* b3  = (const float*)d_in[10];
    const float* w4  = (const float*)d_in[11];
    const float* g4  = (const float*)d_in[12];
    const float* b4  = (const float*)d_in[13];
    const float* w5  = (const float*)d_in[14];
    const float* g5  = (const float*)d_in[15];
    const float* b5  = (const float*)d_in[16];
    const float* lw1 = (const float*)d_in[17];
    const float* lb1 = (const float*)d_in[18];
    const float* lw2 = (const float*)d_in[19];
    const float* lb2 = (const float*)d_in[20];
    const float* lw3 = (const float*)d_in[21];
    const float* lb3 = (const float*)d_in[22];
    const float* cw  = (const float*)d_in[23];
    float* out = (float*)d_out;

    float* ws   = (float*)d_ws;
    float* h512 = ws;                      // B*N*512 = 4194304
    float* G    = h512 + 4194304;          // 2097152 (B*N*256 max)
    float* Hb   = G + 2097152;             // 2097152
    float* ymax = Hb + 2097152;            // 2097152
    float* ymin = ymax + 2097152;          // 2097152
    float* y5   = G;                       // alias: B*N*1024 = 8388608 = G..ymin
    float* fcn  = ymin + 2097152;          // 1048576 (B*128*N max)
    float* fnc1 = fcn + 1048576;           // 32768 (B*N*3 padded)
    float* xx   = fnc1 + 32768;            // 8192
    float* psum = xx + 8192;               // 131072 (512*256)
    float* psq  = psum + 131072;           // 131072
    float* ss   = psq + 131072;            // 2048
    float* p5s  = ss + 2048;               // 262144 (stats: 64*1024; pool: 256*1024)
    float* p5q  = p5s + 262144;            // 262144
    float* ss5  = p5q + 262144;            // 2048
    float* z    = ss5 + 2048;              // 8192
    float* z1   = z + 8192;                // 1024
    float* est  = z1 + 1024;               // 128
    int*   idx  = (int*)(est + 128);       // B*N*20 ints

    for (int which = 0; which < 2; ++which) {
        const float* xin = which ? x2 : x1;
        // ---- layer 1 (C=3 -> 64, choff 0)
        transpose_x_kernel<<<32, 256, 0, stream>>>(xin, fnc1, xx);
        knn_kernel<3><<<1024, 512, 0, stream>>>(xin, fnc1, 3, 0, xx, idx);
        gemm_gh_kernel<3, 64><<<1024, 256, 0, stream>>>(fnc1, 3, 0, w1, G, Hb);
        gather_kernel<64><<<512, 256, 0, stream>>>(G, Hb, idx, ymax, ymin, psum, psq);
        bnscale_kernel<<<64, 256, 0, stream>>>(psum, psq, 512, 64, 163840.f, g1, b1, ss);
        apply_t_kernel<64><<<128, 256, 0, stream>>>(ymax, ymin, ss, 0, h512, fcn);
        // ---- layer 2 (C=64 -> 64, choff 64)
        norms_kernel<<<32, 256, 0, stream>>>(h512, 0, 64, xx);
        knn_kernel<64><<<1024, 512, 0, stream>>>(fcn, h512, 512, 0, xx, idx);
        gemm_gh_kernel<64, 64><<<1024, 256, 0, stream>>>(h512, 512, 0, w2, G, Hb);
        gather_kernel<64><<<512, 256, 0, stream>>>(G, Hb, idx, ymax, ymin, psum, psq);
        bnscale_kernel<<<64, 256, 0, stream>>>(psum, psq, 512, 64, 163840.f, g2, b2, ss);
        apply_t_kernel<64><<<128, 256, 0, stream>>>(ymax, ymin, ss, 64, h512, fcn);
        // ---- layer 3 (C=64 -> 128, choff 128)
        norms_kernel<<<32, 256, 0, stream>>>(h512, 64, 64, xx);
        knn_kernel<64><<<1024, 512, 0, stream>>>(fcn, h512, 512, 64, xx, idx);
        gemm_gh_kernel<64, 128><<<1024, 256, 0, stream>>>(h512, 512, 64, w3, G, Hb);
        gather_kernel<128><<<512, 256, 0, stream>>>(G, Hb, idx, ymax, ymin, psum, psq);
        bnscale_kernel<<<128, 256, 0, stream>>>(psum, psq, 512, 128, 163840.f, g3, b3, ss);
        apply_t_kernel<128><<<256, 256, 0, stream>>>(ymax, ymin, ss, 128, h512, fcn);
        // ---- layer 4 (C=128 -> 256, choff 256)
        norms_kernel<<<32, 256, 0, stream>>>(h512, 128, 128, xx);
        knn_kernel<128><<<1024, 512, 0, stream>>>(fcn, h512, 512, 128, xx, idx);
        gemm_gh_kernel<128, 256><<<1024, 256, 0, stream>>>(h512, 512, 128, w4, G, Hb);
        gather_kernel<256><<<512, 256, 0, stream>>>(G, Hb, idx, ymax, ymin, psum, psq);
        bnscale_kernel<<<256, 256, 0, stream>>>(psum, psq, 512, 256, 163840.f, g4, b4, ss);
        apply_kernel<<<8192, 256, 0, stream>>>(ymax, ymin, ss, 8, 256, h512);
        // ---- conv1d (512 -> 1024) + fused stats + BN + act + max/mean pool
        gemm5_kernel<<<512, 256, 0, stream>>>(h512, w5, y5, p5s, p5q);
        bnscale_kernel<<<1024, 256, 0, stream>>>(p5s, p5q, 64, 1024, 8192.f, g5, b5, ss5);
        pool_part_kernel<<<256, 256, 0, stream>>>(y5, ss5, p5s, p5q);
        pool_comb_kernel<<<4, 256, 0, stream>>>(p5s, p5q, z);
        // ---- head
        gemv1_kernel<<<256, 64, 0, stream>>>(z, lw1, lb1, z1);
        head2_kernel<<<1, 1024, 0, stream>>>(z1, lw2, lb2, lw3, lb3, cw, out, est, which);
    }
    sim_kernel<<<1, 64, 0, stream>>>(est, out);
}